// Round 11
// baseline (111.599 us; speedup 1.0000x reference)
//
#include <hip/hip_runtime.h>
#include <hip/hip_bf16.h>

// MoE top-1, expert-grouped, zero global atomics, float4 weight staging.
// N=8192 tokens, D=256, H=64, E=32, fp32 (no fp32 MFMA on CDNA4 -> VALU).
// Pipeline: router(256 blk) -> scatter(32 blk) -> ffn(544 blk).
//
// ws ints: hist[256][32] @0 | eidx[8192] @8192 | perm[8192] @16384
//          | counts[32] @24576

constexpr int D = 256;
constexpr int H = 64;
constexpr int E = 32;
constexpr int T_TILE = 16;
constexpr int MAX_TILES = 544;   // sum ceil(c_e/16) <= 541
constexpr int HIST = 0;
constexpr int EIDX = 8192;
constexpr int PERM = 16384;
constexpr int WCNT = 24576;

__device__ __forceinline__ float quad_reduce(float v) {
    // sum across the 4 lanes of each quad via DPP quad_perm (VALU-only)
    int i1 = __builtin_bit_cast(int, v);
    v += __builtin_bit_cast(float,
        __builtin_amdgcn_mov_dpp(i1, 0xB1, 0xF, 0xF, true));   // [1,0,3,2]
    int i2 = __builtin_bit_cast(int, v);
    v += __builtin_bit_cast(float,
        __builtin_amdgcn_mov_dpp(i2, 0x4E, 0xF, 0xF, true));   // [2,3,0,1]
    return v;
}

// ---------------- router (unchanged from passing round 8) ----------------
__global__ __launch_bounds__(256) void router_kernel(
    const float* __restrict__ x, const float* __restrict__ rw,
    const float* __restrict__ rb, int* __restrict__ ws)
{
    __shared__ float4 xs[32][65];
    __shared__ float4 rwt[64][33];     // [k4][e], padded
    __shared__ float logitS[32][E + 1];
    __shared__ int lcnt[E];

    const int t = threadIdx.x;
    const int n0 = blockIdx.x * 32;
    if (t < E) lcnt[t] = 0;

    const float4* x4 = (const float4*)x;
    const float4* rw4 = (const float4*)rw;
    for (int i = t; i < 32 * 64; i += 256) {
        int r = i >> 6, q = i & 63;
        xs[r][q] = x4[(size_t)(n0 + r) * 64 + q];
        rwt[q][r] = rw4[i];            // i = r*64+q : coalesced global read
    }
    __syncthreads();

    {
        const int e = t & 31, g = t >> 5;
        float s[4];
#pragma unroll
        for (int j = 0; j < 4; ++j) s[j] = rb[e];
#pragma unroll
        for (int p = 0; p < 8; ++p) {
            float sp[4] = {0.f, 0.f, 0.f, 0.f};
#pragma unroll
            for (int k4 = 0; k4 < 8; ++k4) {
                float4 wv = rwt[p * 8 + k4][e];
#pragma unroll
                for (int j = 0; j < 4; ++j) {
                    float4 xv = xs[g * 4 + j][p * 8 + k4];
                    sp[j] = fmaf(xv.x, wv.x, sp[j]);
                    sp[j] = fmaf(xv.y, wv.y, sp[j]);
                    sp[j] = fmaf(xv.z, wv.z, sp[j]);
                    sp[j] = fmaf(xv.w, wv.w, sp[j]);
                }
            }
#pragma unroll
            for (int j = 0; j < 4; ++j) s[j] += sp[j];
        }
#pragma unroll
        for (int j = 0; j < 4; ++j) logitS[g * 4 + j][e] = s[j];
    }
    __syncthreads();

    if (t < 32) {
        float best = logitS[t][0];
        int bi = 0;
#pragma unroll
        for (int i = 1; i < E; ++i) {
            float v = logitS[t][i];
            if (v > best) { best = v; bi = i; }   // strict >: first occurrence
        }
        ws[EIDX + n0 + t] = bi;
        atomicAdd(&lcnt[bi], 1);                  // LDS atomic only
    }
    __syncthreads();
    if (t < E) ws[HIST + blockIdx.x * E + t] = lcnt[t];
}

// ---------------- scatter (unchanged from passing round 8) ----------------
__global__ __launch_bounds__(256) void scatter_kernel(int* __restrict__ ws)
{
    __shared__ int cfull[8][E], cbelow[8][E];
    __shared__ int cnts_s[E], below_s[E], offs_s[E], lcnt[E];

    const int t = threadIdx.x;
    const int b = blockIdx.x;
    const int c = t >> 5, e = t & 31;
    const int rlim = 8 * b;

    int full = 0, below = 0;
    for (int i = 0; i < 32; ++i) {
        const int r = c * 32 + i;
        const int v = ws[HIST + r * E + e];
        full += v;
        if (r < rlim) below += v;
    }
    cfull[c][e] = full; cbelow[c][e] = below;
    __syncthreads();
    if (t < E) {
        int tot = 0, bg = 0;
#pragma unroll
        for (int c2 = 0; c2 < 8; ++c2) { tot += cfull[c2][t]; bg += cbelow[c2][t]; }
        cnts_s[t] = tot; below_s[t] = bg; lcnt[t] = 0;
    }
    __syncthreads();
    if (t == 0) {
        int off = 0;
        for (int e2 = 0; e2 < E; ++e2) { offs_s[e2] = off; off += cnts_s[e2]; }
    }
    __syncthreads();
    {
        const int n = b * 256 + t;
        const int e2 = ws[EIDX + n];
        const int r = atomicAdd(&lcnt[e2], 1);
        ws[PERM + offs_s[e2] + below_s[e2] + r] = n;
    }
    if (b == 0 && t < E) ws[WCNT + t] = cnts_s[t];
}

// ---------------- ffn ----------------
// Fragment remap vs round 8: thread owns 4 CONSECUTIVE cols {4q+j}.
//  -> W1/W2 staging = float4 loads (16 instead of 64 scalars per GEMM)
//  -> part/out writes linear in lane (bank/store floor).
// Arithmetic bit-identical to passing round 8 (same k-order chains, same
// quad-reduce tree, same cross-wave sum order).
__global__ __launch_bounds__(256) void ffn_kernel(
    const float* __restrict__ x,
    const float* __restrict__ W1, const float* __restrict__ b1,
    const float* __restrict__ W2, const float* __restrict__ b2,
    const int* __restrict__ ws, float* __restrict__ out)
{
    __shared__ float part[4][T_TILE][H];   // 16 KB
    __shared__ float hsl[T_TILE][H];       // 4 KB
    __shared__ int rowsl[T_TILE];
    __shared__ int cs[E];

    const int t = threadIdx.x;
    if (t < E) cs[t] = ws[WCNT + t];
    __syncthreads();

    // self-locate (uniform across block; every thread computes it)
    int e = -1, start = 0, cnt = 0;
    {
        int b = blockIdx.x, off = 0;
#pragma unroll 1
        for (int e2 = 0; e2 < E; ++e2) {
            const int c = cs[e2];
            const int nt = (c + T_TILE - 1) >> 4;
            if (e < 0) {
                if (b < nt) { e = e2; start = off + b * T_TILE;
                              cnt = min(T_TILE, c - b * T_TILE); }
                else b -= nt;
            }
            off += c;
        }
    }
    if (e < 0) return;

    const int lane = t & 63;
    const int w = t >> 6;
    const int s = lane & 3;
    const int q = lane >> 2;

    if (t < T_TILE)
        rowsl[t] = ws[PERM + start + (t < cnt ? t : 0)];

    // W1 fragment: 16 float4 loads (cols 4q..4q+3, k-slice (4w+s)*16..+16)
    const float* w1e = W1 + (size_t)e * (D * H);
    float4 w1v[16];
    {
        const float* base = w1e + (size_t)((w * 4 + s) * 16) * H + 4 * q;
#pragma unroll
        for (int k = 0; k < 16; ++k)
            w1v[k] = *(const float4*)(base + k * H);
    }
    __syncthreads();

#define LOADX(buf, row) {                                                  \
        const float* xb_ = x + (size_t)(row) * D + (w * 4 + s) * 16;       \
        buf[0] = *(const float4*)(xb_ + 0);                                \
        buf[1] = *(const float4*)(xb_ + 4);                                \
        buf[2] = *(const float4*)(xb_ + 8);                                \
        buf[3] = *(const float4*)(xb_ + 12); }

#define BODY1(tok, xb) {                                                   \
        float sp0 = 0.f, sp1 = 0.f, sp2 = 0.f, sp3 = 0.f;                  \
        _Pragma("unroll")                                                  \
        for (int k4 = 0; k4 < 4; ++k4) {                                   \
            float4 xv = xb[k4];                                            \
            _Pragma("unroll")                                              \
            for (int m = 0; m < 4; ++m) {                                  \
                const int k = k4 * 4 + m;                                  \
                const float xs_ = (m == 0) ? xv.x : (m == 1) ? xv.y        \
                                 : (m == 2) ? xv.z : xv.w;                 \
                sp0 = fmaf(xs_, w1v[k].x, sp0);                            \
                sp1 = fmaf(xs_, w1v[k].y, sp1);                            \
                sp2 = fmaf(xs_, w1v[k].z, sp2);                            \
                sp3 = fmaf(xs_, w1v[k].w, sp3);                            \
            }                                                              \
        }                                                                  \
        sp0 = quad_reduce(sp0); sp1 = quad_reduce(sp1);                    \
        sp2 = quad_reduce(sp2); sp3 = quad_reduce(sp3);                    \
        float a_ = (s & 1) ? sp1 : sp0;                                    \
        float c_ = (s & 1) ? sp3 : sp2;                                    \
        part[w][tok][4 * q + s] = (s & 2) ? c_ : a_; }

    {
        float4 xa[4], xb4[4];
        LOADX(xa, rowsl[0]);
        for (int tok = 0; tok < cnt; tok += 2) {
            if (tok + 1 < cnt) LOADX(xb4, rowsl[tok + 1]);
            BODY1(tok, xa);
            if (tok + 1 < cnt) {
                if (tok + 2 < cnt) LOADX(xa, rowsl[tok + 2]);
                BODY1(tok + 1, xb4);
            }
        }
    }

    // W2 fragment: 16 float4 loads (d-cols 64w+4q..+3, h-slice 16s..16s+16)
    const float* w2e = W2 + (size_t)e * (H * D);
    float4 w2v[16];
    {
        const float* base = w2e + (size_t)(16 * s) * D + 64 * w + 4 * q;
#pragma unroll
        for (int k = 0; k < 16; ++k)
            w2v[k] = *(const float4*)(base + k * D);
    }
    const float b2v = b2[e * D + 64 * w + 4 * q + s];
    __syncthreads();

    // cross-wave reduce + bias + relu -> hsl
    {
        const int h = t & 63;
        const int tq = t >> 6;
        const float b1v = b1[e * H + h];
#pragma unroll
        for (int r = 0; r < 4; ++r) {
            const int tok = tq * 4 + r;
            if (tok < cnt) {
                float v = part[0][tok][h] + part[1][tok][h]
                        + part[2][tok][h] + part[3][tok][h] + b1v;
                hsl[tok][h] = fmaxf(v, 0.f);
            }
        }
    }
    __syncthreads();

#define LOADH(buf, tok) {                                                  \
        const float* hb_ = &hsl[tok][s * 16];                              \
        buf[0] = *(const float4*)(hb_ + 0);                                \
        buf[1] = *(const float4*)(hb_ + 4);                                \
        buf[2] = *(const float4*)(hb_ + 8);                                \
        buf[3] = *(const float4*)(hb_ + 12); }

#define BODY2(tok, hb) {                                                   \
        float sp0 = 0.f, sp1 = 0.f, sp2 = 0.f, sp3 = 0.f;                  \
        _Pragma("unroll")                                                  \
        for (int k4 = 0; k4 < 4; ++k4) {                                   \
            float4 hv = hb[k4];                                            \
            _Pragma("unroll")                                              \
            for (int m = 0; m < 4; ++m) {                                  \
                const int k = k4 * 4 + m;                                  \
                const float hs_ = (m == 0) ? hv.x : (m == 1) ? hv.y        \
                                 : (m == 2) ? hv.z : hv.w;                 \
                sp0 = fmaf(hs_, w2v[k].x, sp0);                            \
                sp1 = fmaf(hs_, w2v[k].y, sp1);                            \
                sp2 = fmaf(hs_, w2v[k].z, sp2);                            \
                sp3 = fmaf(hs_, w2v[k].w, sp3);                            \
            }                                                              \
        }                                                                  \
        sp0 = quad_reduce(sp0); sp1 = quad_reduce(sp1);                    \
        sp2 = quad_reduce(sp2); sp3 = quad_reduce(sp3);                    \
        float a_ = (s & 1) ? sp1 : sp0;                                    \
        float c_ = (s & 1) ? sp3 : sp2;                                    \
        const float val_ = ((s & 2) ? c_ : a_) + b2v;                      \
        const int row_ = rowsl[tok];                                       \
        out[(size_t)row_ * D + 64 * w + 4 * q + s] = fmaxf(val_, 0.f); }

    {
        float4 ha[4], hb4[4];
        LOADH(ha, 0);
        for (int tok = 0; tok < cnt; tok += 2) {
            if (tok + 1 < cnt) LOADH(hb4, tok + 1);
            BODY2(tok, ha);
            if (tok + 1 < cnt) {
                if (tok + 2 < cnt) LOADH(ha, tok + 2);
                BODY2(tok + 1, hb4);
            }
        }
    }
#undef LOADX
#undef BODY1
#undef LOADH
#undef BODY2
}

extern "C" void kernel_launch(void* const* d_in, const int* in_sizes, int n_in,
                              void* d_out, int out_size, void* d_ws, size_t ws_size,
                              hipStream_t stream) {
    const float* x  = (const float*)d_in[0];
    const float* rw = (const float*)d_in[1];
    const float* rb = (const float*)d_in[2];
    const float* W1 = (const float*)d_in[3];
    const float* b1 = (const float*)d_in[4];
    const float* W2 = (const float*)d_in[5];
    const float* b2 = (const float*)d_in[6];
    float* out = (float*)d_out;
    int* ws = (int*)d_ws;

    const int N = in_sizes[0] / D;   // 8192

    router_kernel<<<N / 32, 256, 0, stream>>>(x, rw, rb, ws);
    scatter_kernel<<<N / 256, 256, 0, stream>>>(ws);
    ffn_kernel<<<MAX_TILES, 256, 0, stream>>>(x, W1, b1, W2, b2, ws, out);
}